// Round 8
// baseline (234.815 us; speedup 1.0000x reference)
//
#include <hip/hip_runtime.h>
#include <math.h>
#include <stdint.h>

#define Bn 8
#define Nn 2048
#define Cn 128
#define CP 144          // padded cols: 128 h-cols + w-col(=128) + 15 zero cols
#define NKB (Nn / 32)   // 64 k-blocks of 32

typedef _Float16 f16x8 __attribute__((ext_vector_type(8)));
typedef _Float16 f16x4 __attribute__((ext_vector_type(4)));
typedef _Float16 f16x2 __attribute__((ext_vector_type(2)));
typedef __fp16   fp16x2 __attribute__((ext_vector_type(2)));
typedef float    f32x4 __attribute__((ext_vector_type(4)));

// ---------------------------------------------------------------------------
// prep_kernel: v[c] = sum_d Ww[d][c]*aw[C+d] (128 parallel dot products),
// vout[128] = b2 = Wb·aw2.  One 256-thread block, ~3 µs.
// ---------------------------------------------------------------------------
__global__ __launch_bounds__(256) void prep_kernel(const float* __restrict__ Ww,
                                                   const float* __restrict__ Wb,
                                                   const float* __restrict__ aw,
                                                   float* __restrict__ vout) {
    int tid = threadIdx.x;
    if (tid < 128) {
        float acc = 0.f;
#pragma unroll 16
        for (int d = 0; d < Cn; ++d) acc += Ww[d * Cn + tid] * aw[Cn + d];
        vout[tid] = acc;
    } else if (tid < 192) {              // wave 2, lanes 0..63
        int i = tid - 128;
        float p = Wb[i] * aw[Cn + i] + Wb[i + 64] * aw[Cn + i + 64];
        p += __shfl_xor(p, 32, 64);
        p += __shfl_xor(p, 16, 64);
        p += __shfl_xor(p, 8, 64);
        p += __shfl_xor(p, 4, 64);
        p += __shfl_xor(p, 2, 64);
        p += __shfl_xor(p, 1, 64);
        if (i == 0) vout[128] = p;
    }
}

// ---------------------------------------------------------------------------
// rows_kernel: per 16-row chunk: w = exp(h·v + b2),
//   hWt[b][kb][cp][ks] = f16(w_j*h[j][cp]) (cp<128), f16(w_j) at cp=128,
//   zeros cp 129..143.  Reads only h (2 KB/row) + v (516 B) — no Ww.
// grid = 8 x 128 = 1024 blocks, 256 threads.
// ---------------------------------------------------------------------------
__global__ __launch_bounds__(256) void rows_kernel(const float* __restrict__ h,
                                                   const float* __restrict__ vout,
                                                   _Float16* __restrict__ hWt) {
    __shared__ float tile[16][132];
    __shared__ float vsh[129];
    __shared__ float wsh[16];

    int bid = blockIdx.x;
    int b   = bid & 7;                   // XCD-aligned batch
    int n0  = (bid >> 3) << 4;
    int tid = threadIdx.x;

    if (tid < 129) vsh[tid] = vout[tid];
    {   // stage 16x128 h tile: 512 float4, 2 per thread
#pragma unroll
        for (int i = 0; i < 2; ++i) {
            int idx = tid + 256 * i;
            int r = idx >> 5, f4 = idx & 31;
            *(float4*)&tile[r][f4 * 4] =
                ((const float4*)(h + (size_t)(b * Nn + n0 + r) * Cn))[f4];
        }
    }
    __syncthreads();

    {   // w = exp(h·v + b2): 16 threads per row, 8 elems each
        int r = tid >> 4, g = tid & 15;
        float acc = 0.f;
#pragma unroll
        for (int ii = 0; ii < 8; ++ii) {
            int i = g * 8 + ii;
            acc += tile[r][i] * vsh[i];
        }
        acc += __shfl_xor(acc, 1, 64);
        acc += __shfl_xor(acc, 2, 64);
        acc += __shfl_xor(acc, 4, 64);
        acc += __shfl_xor(acc, 8, 64);
        if (g == 0) wsh[r] = expf(acc + vsh[128]);
    }
    __syncthreads();

    {   // hWt stores: 144 cp x 8 pairs = 1152 f16x2
        int kb = n0 >> 5, khalf = (n0 >> 4) & 1;
        _Float16* hWb = hWt + ((size_t)(b * NKB + kb) * CP) * 32 + khalf * 16;
#pragma unroll
        for (int i = 0; i < 5; ++i) {
            int idx = tid + 256 * i;
            if (idx < 1152) {
                int cp = idx >> 3, p = idx & 7;
                int r0 = p * 2;
                f16x2 v2;
                if (cp < 128) {
                    v2[0] = (_Float16)(wsh[r0] * tile[r0][cp]);
                    v2[1] = (_Float16)(wsh[r0 + 1] * tile[r0 + 1][cp]);
                } else if (cp == 128) {
                    v2[0] = (_Float16)wsh[r0];
                    v2[1] = (_Float16)wsh[r0 + 1];
                } else {
                    v2[0] = (_Float16)0.f;
                    v2[1] = (_Float16)0.f;
                }
                *(f16x2*)(hWb + (size_t)cp * 32 + p * 2) = v2;
            }
        }
    }
}

// ---------------------------------------------------------------------------
// attn_kernel: f16 GEMM out' = A @ hW (cols 0..127 numerator, col 128
// denominator via MFMA), row-normalize epilogue.
// M=32/block, grid 8x64=512 (2 blocks/CU), 512 thr = 8 waves.
// Wave w owns c-tile w; waves 0/1 also own den tile (cp 128..143) for
// m-tile 0/1.  128 k's per iter (4 chunks of 32) -> 16 iters, 16 barriers
// (half of R7: each barrier's vmcnt(0) drain costs ~an L3 latency).
// A staged f32->f16 in LDS double-buffer; B-frags 1-iter register
// prefetch; A-globals 2-iter prefetch; manual 2x unroll names the buffers.
// ---------------------------------------------------------------------------
__global__ __launch_bounds__(512, 4) void attn_kernel(const float* __restrict__ A,
                                                      const _Float16* __restrict__ hWt,
                                                      float* __restrict__ out) {
    __shared__ _Float16 Af[2][4][32][40];   // [buf][chunk][row][kpad40] f16, 20 KB
    __shared__ float den[32];

    int bid = blockIdx.x;
    int b   = bid & 7;                      // XCD-aligned batch
    int i0  = (bid >> 3) << 5;              // 64 row-blocks of 32
    int tid = threadIdx.x;
    int wv  = tid >> 6, l = tid & 63;
    int m   = l & 15, q = l >> 4;

    const float*    Ab  = A   + (size_t)(b * Nn + i0) * Nn;
    const _Float16* hWb = hWt + (size_t)b * NKB * CP * 32;

    // staging map: idx = i*512+tid -> row = idx>>5 (0..31), slot = idx&31
    int sr0 = tid >> 5, sf4 = tid & 31;     // rows 0..15 (i=0), +16 for i=1
    const float* sgA = Ab + (size_t)sr0 * Nn + sf4 * 4;
    const float* sgB = Ab + (size_t)(sr0 + 16) * Nn + sf4 * 4;
    int sch = sf4 >> 3, skl = (sf4 & 7) * 4;

    f32x4 accc[2];
    f32x4 acc8;
    accc[0] = (f32x4){0.f, 0.f, 0.f, 0.f};
    accc[1] = (f32x4){0.f, 0.f, 0.f, 0.f};
    acc8    = (f32x4){0.f, 0.f, 0.f, 0.f};

    auto cvtst = [&](int t, int row, float4 v) {
        union { fp16x2 h2[2]; f16x4 v4; } u;
        u.h2[0] = __builtin_amdgcn_cvt_pkrtz(v.x, v.y);
        u.h2[1] = __builtin_amdgcn_cvt_pkrtz(v.z, v.w);
        *(f16x4*)&Af[t & 1][sch][row][skl] = u.v4;
    };
    auto loadB = [&](int t, f16x8* bf) {    // bf[0..3]=own c; bf[4..7]=den tile
#pragma unroll
        for (int ck = 0; ck < 4; ++ck)
            bf[ck] = *(const f16x8*)(hWb + ((size_t)(4 * t + ck) * CP + wv * 16 + m) * 32 + q * 8);
        if (wv < 2) {
#pragma unroll
            for (int ck = 0; ck < 4; ++ck)
                bf[4 + ck] = *(const f16x8*)(hWb + ((size_t)(4 * t + ck) * CP + 128 + m) * 32 + q * 8);
        }
    };
    auto compute = [&](int buf, const f16x8* bf) {
#pragma unroll
        for (int ck = 0; ck < 4; ++ck) {
            f16x8 af0 = *(const f16x8*)&Af[buf][ck][m][q * 8];
            f16x8 af1 = *(const f16x8*)&Af[buf][ck][16 + m][q * 8];
            accc[0] = __builtin_amdgcn_mfma_f32_16x16x32_f16(af0, bf[ck], accc[0], 0, 0, 0);
            accc[1] = __builtin_amdgcn_mfma_f32_16x16x32_f16(af1, bf[ck], accc[1], 0, 0, 0);
            if (wv < 2)
                acc8 = __builtin_amdgcn_mfma_f32_16x16x32_f16(wv ? af1 : af0, bf[4 + ck],
                                                              acc8, 0, 0, 0);
        }
    };

    // preamble: A(0),A(1) in regs; B(0) in bfA; buf0 <- A(0)
    float4 a0x = *(const float4*)(sgA);
    float4 a0y = *(const float4*)(sgB);
    float4 a1x = *(const float4*)(sgA + 128);
    float4 a1y = *(const float4*)(sgB + 128);
    f16x8 bfA[8], bfB[8];
    loadB(0, bfA);
    cvtst(0, sr0, a0x);
    cvtst(0, sr0 + 16, a0y);
    __syncthreads();

    for (int t2 = 0; t2 < 8; ++t2) {
        int te = 2 * t2, to = te + 1;
        // iter te (even, buf0, frags bfA)
        loadB(to, bfB);
        if (t2 < 7) {
            a0x = *(const float4*)(sgA + (te + 2) * 128);
            a0y = *(const float4*)(sgB + (te + 2) * 128);
        }
        compute(0, bfA);
        cvtst(to, sr0, a1x);                // buf1 <- A(te+1)
        cvtst(to, sr0 + 16, a1y);
        __syncthreads();
        // iter to (odd, buf1, frags bfB)
        if (t2 < 7) {
            loadB(to + 1, bfA);
            a1x = *(const float4*)(sgA + (to + 2) * 128);
            a1y = *(const float4*)(sgB + (to + 2) * 128);
        }
        compute(1, bfB);
        if (t2 < 7) {
            cvtst(to + 1, sr0, a0x);        // buf0 <- A(te+2)
            cvtst(to + 1, sr0 + 16, a0y);
        }
        __syncthreads();
    }

    // denominator: D col 0 of den tile = cp 128 = w-column
    if (wv < 2 && m == 0) {
#pragma unroll
        for (int r = 0; r < 4; ++r) den[wv * 16 + q * 4 + r] = acc8[r];
    }
    __syncthreads();

#pragma unroll
    for (int mt = 0; mt < 2; ++mt) {
#pragma unroll
        for (int r = 0; r < 4; ++r) {
            int row = mt * 16 + q * 4 + r;
            float invd = 1.f / den[row];
            out[(size_t)(b * Nn + i0 + row) * Cn + wv * 16 + m] = accc[mt][r] * invd;
        }
    }
}

// ---------------------------------------------------------------------------
extern "C" void kernel_launch(void* const* d_in, const int* in_sizes, int n_in,
                              void* d_out, int out_size, void* d_ws, size_t ws_size,
                              hipStream_t stream) {
    const float* h  = (const float*)d_in[0];
    const float* A  = (const float*)d_in[1];
    const float* Ww = (const float*)d_in[2];
    const float* Wb = (const float*)d_in[3];
    const float* aw = (const float*)d_in[4];
    // d_in[5] = a_b : cancels in the row normalization, unused
    float* out = (float*)d_out;

    char* ws = (char*)d_ws;
    _Float16* hWt  = (_Float16*)ws;                                  // 4.72 MB
    float*    vout = (float*)(ws + (size_t)Bn * NKB * CP * 32 * 2);  // 129 f32

    prep_kernel<<<1, 256, 0, stream>>>(Ww, Wb, aw, vout);
    rows_kernel<<<Bn * (Nn / 16), 256, 0, stream>>>(h, vout, hWt);
    attn_kernel<<<Bn * (Nn / 32), 512, 0, stream>>>(A, hWt, out);
}